// Round 20
// baseline (174.256 us; speedup 1.0000x reference)
//
#include <hip/hip_runtime.h>
#include <math.h>

#define NTHREADS 256
constexpr int TB = 4096;   // batch
constexpr int TT = 96;     // time
constexpr int TN = 32;     // channels
constexpr int XLD = 33;    // padded LDS leading dim

struct Params {
    const float* x; const float* noise;
    const float* w_start; const float* b_start;
    const float* wg; const float* bg; const float* wn; const float* bn;
    const float* ew[16];   // e0_w1,e0_b1,e0_w2,e0_b2, e1_w1, ...
    float* out; float* part;
};

// gelu tanh-approx via sigmoid identity: 0.5v(1+tanh(u)) = v*sigmoid(2u)
__device__ __forceinline__ float gelu_f(float v) {
    float v2 = v * v;
    float u2 = fmaf(0.0713548162726278f * v, v2, 1.5957691216057308f * v);
    float t = __expf(-u2);
    return v * __builtin_amdgcn_rcpf(1.0f + t);
}

// Full-patch dual-window accumulate: patch at window-offset X0 (compile-time), both
// 24-row windows share one weight stream. Weights via wave-uniform compile-time-offset
// global reads -> scalar K$ path. No partial patches (24 = lcm(8,6,4,12)).
template<int P, int X0>
__device__ __forceinline__ void patchF(const float (&x0)[24], const float (&x1)[24],
        const float* __restrict__ w1, const float* __restrict__ w2,
        const float* __restrict__ b1, const float* __restrict__ b2,
        float g, float (&y0)[24], float (&y1)[24]) {
    #pragma unroll 2
    for (int jb = 0; jb < 8; ++jb) {
        float aA0 = b1[jb * 4 + 0], aA1 = b1[jb * 4 + 1];
        float aA2 = b1[jb * 4 + 2], aA3 = b1[jb * 4 + 3];
        float aB0 = aA0, aB1 = aA1, aB2 = aA2, aB3 = aA3;
        #pragma unroll
        for (int l = 0; l < P; ++l) {
            const float vA = x0[X0 + l];
            const float vB = x1[X0 + l];
            const float w0 = w1[l * 32 + jb * 4 + 0];
            const float w1v = w1[l * 32 + jb * 4 + 1];
            const float w2v = w1[l * 32 + jb * 4 + 2];
            const float w3 = w1[l * 32 + jb * 4 + 3];
            aA0 = fmaf(vA, w0, aA0);  aA1 = fmaf(vA, w1v, aA1);
            aA2 = fmaf(vA, w2v, aA2); aA3 = fmaf(vA, w3, aA3);
            aB0 = fmaf(vB, w0, aB0);  aB1 = fmaf(vB, w1v, aB1);
            aB2 = fmaf(vB, w2v, aB2); aB3 = fmaf(vB, w3, aB3);
        }
        float hA[4], hB[4];
        hA[0] = g * gelu_f(aA0); hA[1] = g * gelu_f(aA1);
        hA[2] = g * gelu_f(aA2); hA[3] = g * gelu_f(aA3);
        hB[0] = g * gelu_f(aB0); hB[1] = g * gelu_f(aB1);
        hB[2] = g * gelu_f(aB2); hB[3] = g * gelu_f(aB3);
        #pragma unroll
        for (int l = 0; l < P; ++l) {
            float accA = y0[X0 + l];
            float accB = y1[X0 + l];
            #pragma unroll
            for (int q = 0; q < 4; ++q) {
                const float w = w2[(jb * 4 + q) * P + l];
                accA = fmaf(hA[q], w, accA);
                accB = fmaf(hB[q], w, accB);
            }
            y0[X0 + l] = accA;
            y1[X0 + l] = accB;
        }
    }
    #pragma unroll
    for (int l = 0; l < P; ++l) {
        y0[X0 + l] = fmaf(g, b2[l], y0[X0 + l]);
        y1[X0 + l] = fmaf(g, b2[l], y1[X0 + l]);
    }
}

// ================= K1: DFT + selection + trend/season + gating =================
__global__ __launch_bounds__(NTHREADS) void ams_k1(Params p) {
    __shared__ float xs[TT * XLD];       // 12.7 KB
    __shared__ float ct[96], st[96];
    __shared__ float xlin[96];
    __shared__ float selr[256], seli[256];   // [q][n]
    __shared__ int   selk[256];
    __shared__ int   selcnt[32];
    __shared__ float wst[32];
    __shared__ float gtmp[8];
    __shared__ float b0sh;

    const int tid = threadIdx.x;
    const int b = blockIdx.x;

    // ---- stage x, twiddles ----
    const float* xb = p.x + (size_t)b * (TT * TN);
    #pragma unroll 1
    for (int idx = tid; idx < TT * TN; idx += NTHREADS)
        xs[(idx >> 5) * XLD + (idx & 31)] = xb[idx];
    if (tid < 96) {
        float ang = (float)tid * 0.06544984694978735f;  // 2*pi/96
        ct[tid] = cosf(ang);
        st[tid] = sinf(ang);
    }
    if (tid < 32) wst[tid] = p.w_start[tid];
    if (tid == 0) b0sh = p.b_start[0];
    __syncthreads();

    // ---- Cooley-Tukey DFT (96 = 8x12) + fused wave-parallel top-3 ----
    {
        const int n = tid >> 3;
        const int kslot = tid & 7;
        const int lane = tid & 63;

        float Sr[12], Si[12];
        #pragma unroll
        for (int bb = 0; bb < 12; ++bb) { Sr[bb] = 0.0f; Si[bb] = 0.0f; }
        {
            const int step = 12 * kslot;
            int idx8 = 0;
            #pragma unroll 2
            for (int a = 0; a < 8; ++a) {
                float c8 = ct[idx8], s8 = st[idx8];
                idx8 += step; idx8 = (idx8 >= 96) ? idx8 - 96 : idx8;
                const float* xrow = &xs[(12 * a) * XLD + n];
                #pragma unroll
                for (int bb = 0; bb < 12; ++bb) {
                    float xv = xrow[bb * XLD];
                    Sr[bb] = fmaf(xv, c8, Sr[bb]);
                    Si[bb] = fmaf(xv, s8, Si[bb]);
                }
            }
        }

        float ar[7], ai[7];
        #pragma unroll
        for (int u = 0; u < 7; ++u) {
            const int k = kslot + 8 * u;
            const float ckv = ct[k];
            const float skv = st[k];
            float cb = 1.0f, sb = 0.0f, arx = 0.0f, aix = 0.0f;
            #pragma unroll
            for (int bb = 0; bb < 12; ++bb) {
                arx = fmaf(cb, Sr[bb], arx);
                arx = fmaf(-sb, Si[bb], arx);
                aix = fmaf(cb, Si[bb], aix);
                aix = fmaf(sb, Sr[bb], aix);
                float cn = fmaf(cb, ckv, -(sb * skv));
                float sn = fmaf(sb, ckv,  cb * skv);
                cb = cn; sb = sn;
            }
            ar[u] = arx; ai[u] = aix;
        }

        float amp[7];
        #pragma unroll
        for (int u = 0; u < 7; ++u) {
            int k = kslot + 8 * u;
            amp[u] = (k == 0) ? 0.0f : ((k <= 48) ? sqrtf(ar[u] * ar[u] + ai[u] * ai[u]) : -1.0f);
        }
        float v1 = -2.0f, v2 = -2.0f, v3 = -2.0f;
        #pragma unroll
        for (int u = 0; u < 7; ++u) {
            float a = amp[u];
            if (a > v1)      { v3 = v2; v2 = v1; v1 = a; }
            else if (a > v2) { v3 = v2; v2 = a; }
            else if (a > v3) { v3 = a; }
        }
        #pragma unroll
        for (int d = 1; d <= 4; d <<= 1) {
            float b1v = __shfl_xor(v1, d, 64);
            float b2v = __shfl_xor(v2, d, 64);
            float b3v = __shfl_xor(v3, d, 64);
            float m1 = fmaxf(v1, b1v), n1 = fminf(v1, b1v);
            float m2 = fmaxf(v2, b2v), n2 = fminf(v2, b2v);
            float s3 = (v1 > b1v) ? v3 : b3v;
            float c3 = fmaxf(fmaxf(fminf(n1, m2), n2), s3);
            v2 = fmaxf(n1, m2);
            v1 = m1;
            v3 = c3;
        }
        int qc = 0;
        #pragma unroll
        for (int u = 0; u < 7; ++u) qc += (amp[u] >= v3) ? 1 : 0;
        int inc = qc;
        #pragma unroll
        for (int d = 1; d <= 4; d <<= 1) {
            int t = __shfl_up(inc, d, 64);
            if (kslot >= d) inc += t;
        }
        int off = inc - qc;
        int cnt = __shfl(inc, lane | 7, 64);
        if (kslot == 0) selcnt[n] = (cnt < 8) ? cnt : 8;
        int w = off;
        #pragma unroll
        for (int u = 0; u < 7; ++u) {
            int k = kslot + 8 * u;
            if (amp[u] >= v3 && w < 8) {
                float wgt = (k == 0 || k == 48) ? (1.0f / 96.0f) : (2.0f / 96.0f);
                selk[w * 32 + n] = k;
                selr[w * 32 + n] = wgt * ar[u];
                seli[w * 32 + n] = wgt * ai[u];
                w++;
            }
        }
    }
    __syncthreads();

    // ---- trend + season -> x_lin (season via incremental rotators) ----
    {
        float b0 = b0sh;
        const int t0 = tid >> 5;
        const int n  = tid & 31;
        const int cnt = selcnt[n];
        float A0 = 0, B0 = 0, c0 = 1, s0 = 0, c80 = 1, s80 = 0;
        float A1 = 0, B1 = 0, c1 = 1, s1 = 0, c81 = 1, s81 = 0;
        float A2 = 0, B2 = 0, c2 = 1, s2 = 0, c82 = 1, s82 = 0;
        #define SETROT(Q, A, B, C, S, C8, S8) \
            if (Q < cnt) { \
                int k = selk[Q * 32 + n]; \
                A = selr[Q * 32 + n]; B = seli[Q * 32 + n]; \
                int m0 = (t0 * k) % 96; C = ct[m0]; S = st[m0]; \
                int m8 = (8 * k) % 96;  C8 = ct[m8]; S8 = st[m8]; \
            }
        SETROT(0, A0, B0, c0, s0, c80, s80)
        SETROT(1, A1, B1, c1, s1, c81, s81)
        SETROT(2, A2, B2, c2, s2, c82, s82)
        #undef SETROT
        #pragma unroll 1
        for (int j = 0; j < 12; ++j) {
            int t = t0 + 8 * j;
            float xv = xs[t * XLD + n];
            #define XC(tt) xs[(((tt) < 0) ? 0 : (((tt) > 95) ? 95 : (tt))) * XLD + n]
            float s4  = XC(t - 1) + xv + XC(t + 1) + XC(t + 2);
            float s8  = s4  + XC(t - 3) + XC(t - 2) + XC(t + 3) + XC(t + 4);
            float s12 = s8  + XC(t - 5) + XC(t - 4) + XC(t + 5) + XC(t + 6);
            #undef XC
            float trend = (s4 * 0.25f + s8 * 0.125f + s12 * (1.0f / 12.0f)) * (1.0f / 3.0f);
            float season = A0 * c0 + B0 * s0 + A1 * c1 + B1 * s1 + A2 * c2 + B2 * s2;
            float nc0 = fmaf(c0, c80, -(s0 * s80)), ns0 = fmaf(s0, c80, c0 * s80);
            float nc1 = fmaf(c1, c81, -(s1 * s81)), ns1 = fmaf(s1, c81, c1 * s81);
            float nc2 = fmaf(c2, c82, -(s2 * s82)), ns2 = fmaf(s2, c82, c2 * s82);
            c0 = nc0; s0 = ns0; c1 = nc1; s1 = ns1; c2 = nc2; s2 = ns2;
            #pragma unroll 1
            for (int q = 3; q < cnt; ++q) {
                int k = selk[q * 32 + n];
                int m = (t * k) % 96;
                season = fmaf(selr[q * 32 + n], ct[m], season);
                season = fmaf(seli[q * 32 + n], st[m], season);
            }
            float val = (xv + trend + season) * wst[n];
            #pragma unroll
            for (int d = 16; d >= 1; d >>= 1) val += __shfl_xor(val, d, 64);
            if ((tid & 31) == 0) xlin[t] = val + b0;
        }
    }
    __syncthreads();

    // ---- gating GEMV, all threads ----
    {
        int e8 = tid >> 5;
        int tl = tid & 31;
        int eb = e8 & 3;
        const float* W = ((e8 < 4) ? p.wg : p.wn) + eb * 96;
        float acc = 0.0f;
        #pragma unroll
        for (int c = 0; c < 3; ++c)
            acc = fmaf(xlin[tl + 32 * c], W[tl + 32 * c], acc);
        #pragma unroll
        for (int d = 16; d >= 1; d >>= 1) acc += __shfl_xor(acc, d, 64);
        if (tl == 0) gtmp[e8] = acc + ((e8 < 4) ? p.bg[eb] : p.bn[eb]);
    }
    __syncthreads();
    if (tid == 0) {
        float clean[4], stdv[4], noisy[4];
        #pragma unroll
        for (int e = 0; e < 4; ++e) {
            clean[e] = gtmp[e];
            float r = gtmp[4 + e];
            float sp = fmaxf(r, 0.0f) + log1pf(expf(-fabsf(r)));   // softplus
            stdv[e] = fminf(fmaxf(sp + 0.01f, 0.001f), 1000.0f);
            noisy[e] = clean[e] + p.noise[(size_t)b * 4 + e] * stdv[e];
        }
        int i1 = 0, i2 = -1;
        float v1 = -INFINITY, v2 = -INFINITY, v3 = -INFINITY;
        for (int e = 0; e < 4; ++e) if (noisy[e] > v1) { v1 = noisy[e]; i1 = e; }
        for (int e = 0; e < 4; ++e) if (e != i1 && noisy[e] > v2) { v2 = noisy[e]; i2 = e; }
        for (int e = 0; e < 4; ++e) if (e != i1 && e != i2 && noisy[e] > v3) { v3 = noisy[e]; }
        float e2 = expf(v2 - v1);
        float g1 = 1.0f / (1.0f + e2);
        float g2 = e2 * g1;
        float gates[4] = {0.0f, 0.0f, 0.0f, 0.0f};
        gates[i1] = g1; gates[i2] = g2;
        const float inv_sqrt2 = 0.7071067811865476f;
        #pragma unroll
        for (int e = 0; e < 4; ++e) {
            float thr = (noisy[e] > v3) ? v3 : v2;
            float z = (clean[e] - thr) / stdv[e];
            z = fminf(fmaxf(z, -50.0f), 50.0f);
            float pr = 0.5f * (1.0f + erff(z * inv_sqrt2));
            pr = fminf(fmaxf(pr, 0.0f), 1.0f);
            p.part[(size_t)b * 8 + e] = gates[e];
            p.part[(size_t)b * 8 + 4 + e] = pr;
        }
    }
}

// ====== K2: experts, 4 batches/block (1 wave = 1 batch), 24-row full-patch windows ======
__global__ __launch_bounds__(NTHREADS) void ams_k2(Params p) {
    const int tid = threadIdx.x;
    const size_t b = 4 * (size_t)blockIdx.x + (tid >> 6);   // wave-uniform batch
    const int lane = tid & 63;
    const int hi = lane >> 5;    // window pair index 0/1
    const int n = lane & 31;

    const float g0 = p.part[b * 8 + 0];
    const float g1 = p.part[b * 8 + 1];
    const float g2 = p.part[b * 8 + 2];
    const float g3 = p.part[b * 8 + 3];
    const float* xg = p.x + b * (TT * TN);

    // two 24-row x windows: rows [24*hi, 24*hi+24) and [24*hi+48, 24*hi+72)
    float x0[24], x1[24];
    {
        const float* p0 = xg + (24 * hi) * TN + n;
        const float* p1 = xg + (24 * hi + 48) * TN + n;
        #pragma unroll
        for (int r = 0; r < 24; ++r) {
            x0[r] = p0[r * TN];
            x1[r] = p1[r * TN];
        }
    }

    float y0[24], y1[24];
    #pragma unroll
    for (int r = 0; r < 24; ++r) { y0[r] = 0.0f; y1[r] = 0.0f; }

    if (g0 != 0.0f) {   // P=8: 3 full patches per window
        patchF<8, 0>(x0, x1, p.ew[0], p.ew[2], p.ew[1], p.ew[3], g0, y0, y1);
        patchF<8, 8>(x0, x1, p.ew[0], p.ew[2], p.ew[1], p.ew[3], g0, y0, y1);
        patchF<8, 16>(x0, x1, p.ew[0], p.ew[2], p.ew[1], p.ew[3], g0, y0, y1);
    }
    if (g1 != 0.0f) {   // P=6: 4 full patches
        patchF<6, 0>(x0, x1, p.ew[4], p.ew[6], p.ew[5], p.ew[7], g1, y0, y1);
        patchF<6, 6>(x0, x1, p.ew[4], p.ew[6], p.ew[5], p.ew[7], g1, y0, y1);
        patchF<6, 12>(x0, x1, p.ew[4], p.ew[6], p.ew[5], p.ew[7], g1, y0, y1);
        patchF<6, 18>(x0, x1, p.ew[4], p.ew[6], p.ew[5], p.ew[7], g1, y0, y1);
    }
    if (g2 != 0.0f) {   // P=4: 6 full patches
        patchF<4, 0>(x0, x1, p.ew[8], p.ew[10], p.ew[9], p.ew[11], g2, y0, y1);
        patchF<4, 4>(x0, x1, p.ew[8], p.ew[10], p.ew[9], p.ew[11], g2, y0, y1);
        patchF<4, 8>(x0, x1, p.ew[8], p.ew[10], p.ew[9], p.ew[11], g2, y0, y1);
        patchF<4, 12>(x0, x1, p.ew[8], p.ew[10], p.ew[9], p.ew[11], g2, y0, y1);
        patchF<4, 16>(x0, x1, p.ew[8], p.ew[10], p.ew[9], p.ew[11], g2, y0, y1);
        patchF<4, 20>(x0, x1, p.ew[8], p.ew[10], p.ew[9], p.ew[11], g2, y0, y1);
    }
    if (g3 != 0.0f) {   // P=12: 2 full patches
        patchF<12, 0>(x0, x1, p.ew[12], p.ew[14], p.ew[13], p.ew[15], g3, y0, y1);
        patchF<12, 12>(x0, x1, p.ew[12], p.ew[14], p.ew[13], p.ew[15], g3, y0, y1);
    }

    float* o0 = p.out + b * (TT * TN) + (size_t)(24 * hi) * 32 + n;
    float* o1 = o0 + 48 * 32;
    #pragma unroll
    for (int r = 0; r < 24; ++r) {
        o0[r * 32] = y0[r];
        o1[r * 32] = y1[r];
    }
}

__global__ __launch_bounds__(NTHREADS) void ams_finalize(const float* __restrict__ part,
                                                         float* __restrict__ out_loss) {
    __shared__ float red[4][8];
    float acc[8] = {0, 0, 0, 0, 0, 0, 0, 0};
    #pragma unroll 1
    for (int r = threadIdx.x; r < TB; r += NTHREADS) {
        #pragma unroll
        for (int c = 0; c < 8; ++c) acc[c] += part[(size_t)r * 8 + c];
    }
    #pragma unroll
    for (int c = 0; c < 8; ++c) {
        #pragma unroll
        for (int d = 32; d >= 1; d >>= 1) acc[c] += __shfl_xor(acc[c], d, 64);
    }
    int wid = threadIdx.x >> 6;
    if ((threadIdx.x & 63) == 0) {
        #pragma unroll
        for (int c = 0; c < 8; ++c) red[wid][c] = acc[c];
    }
    __syncthreads();
    if (threadIdx.x == 0) {
        float imp[4], load[4];
        #pragma unroll
        for (int c = 0; c < 4; ++c) imp[c]  = red[0][c] + red[1][c] + red[2][c] + red[3][c];
        #pragma unroll
        for (int c = 0; c < 4; ++c) load[c] = red[0][4 + c] + red[1][4 + c] + red[2][4 + c] + red[3][4 + c];
        float mi = (imp[0] + imp[1] + imp[2] + imp[3]) * 0.25f;
        float vi = 0.0f;
        #pragma unroll
        for (int i = 0; i < 4; ++i) { float d = imp[i] - mi; vi += d * d; }
        vi *= (1.0f / 3.0f);
        float ml = (load[0] + load[1] + load[2] + load[3]) * 0.25f;
        float vl = 0.0f;
        #pragma unroll
        for (int i = 0; i < 4; ++i) { float d = load[i] - ml; vl += d * d; }
        vl *= (1.0f / 3.0f);
        float cvi = vi / (mi * mi + 1e-10f);
        float cvl = vl / (ml * ml + 1e-10f);
        out_loss[0] = (cvi + cvl) * 1e-4f;
    }
}

extern "C" void kernel_launch(void* const* d_in, const int* in_sizes, int n_in,
                              void* d_out, int out_size, void* d_ws, size_t ws_size,
                              hipStream_t stream) {
    Params p;
    p.x       = (const float*)d_in[0];
    p.noise   = (const float*)d_in[1];
    p.w_start = (const float*)d_in[2];
    p.b_start = (const float*)d_in[3];
    p.wg      = (const float*)d_in[4];
    p.bg      = (const float*)d_in[5];
    p.wn      = (const float*)d_in[6];
    p.bn      = (const float*)d_in[7];
    for (int i = 0; i < 16; ++i) p.ew[i] = (const float*)d_in[8 + i];
    p.out  = (float*)d_out;
    p.part = (float*)d_ws;   // 4096 * 8 floats = 128 KB of scratch

    ams_k1<<<TB, NTHREADS, 0, stream>>>(p);
    ams_k2<<<TB / 4, NTHREADS, 0, stream>>>(p);
    ams_finalize<<<1, NTHREADS, 0, stream>>>((const float*)d_ws,
                                             (float*)d_out + (size_t)TB * TT * TN);
}

// Round 21
// 163.327 us; speedup vs baseline: 1.0669x; 1.0669x over previous
//
#include <hip/hip_runtime.h>
#include <math.h>

#define NTHREADS 256
constexpr int TB = 4096;   // batch
constexpr int TT = 96;     // time
constexpr int TN = 32;     // channels
constexpr int XLD = 33;    // padded LDS leading dim

struct Params {
    const float* x; const float* noise;
    const float* w_start; const float* b_start;
    const float* wg; const float* bg; const float* wn; const float* bn;
    const float* ew[16];   // e0_w1,e0_b1,e0_w2,e0_b2, e1_w1, ...
    float* out; float* part;
};

// gelu tanh-approx via sigmoid identity: 0.5v(1+tanh(u)) = v*sigmoid(2u)
__device__ __forceinline__ float gelu_f(float v) {
    float v2 = v * v;
    float u2 = fmaf(0.0713548162726278f * v, v2, 1.5957691216057308f * v);
    float t = __expf(-u2);
    return v * __builtin_amdgcn_rcpf(1.0f + t);
}

// Dual-chunk patch accumulate; weights read DIRECTLY from global via wave-uniform
// compile-time-offset addressing -> compiler emits scalar (s_load) K$ reads:
// no LDS staging, no LDS pipe traffic, scalar queue overlaps VALU.
template<int P, int L0, int L1, int CB>
__device__ __forceinline__ void patch_acc2(const float* __restrict__ xg,
        const float* __restrict__ w1, const float* __restrict__ w2,
        const float* __restrict__ b1, const float* __restrict__ b2,
        int pbA, int pbB, int n, float g, float (&yA)[12], float (&yB)[12]) {
    float vA[P], vB[P];
    #pragma unroll
    for (int l = 0; l < P; ++l) {
        vA[l] = xg[(pbA * P + l) * TN + n];
        vB[l] = xg[(pbB * P + l) * TN + n];
    }
    #pragma unroll 2
    for (int jb = 0; jb < 8; ++jb) {
        float aA0 = b1[jb * 4 + 0], aA1 = b1[jb * 4 + 1];
        float aA2 = b1[jb * 4 + 2], aA3 = b1[jb * 4 + 3];
        float aB0 = aA0, aB1 = aA1, aB2 = aA2, aB3 = aA3;
        #pragma unroll
        for (int l = 0; l < P; ++l) {
            const float w0 = w1[l * 32 + jb * 4 + 0];
            const float w1v = w1[l * 32 + jb * 4 + 1];
            const float w2v = w1[l * 32 + jb * 4 + 2];
            const float w3 = w1[l * 32 + jb * 4 + 3];
            aA0 = fmaf(vA[l], w0, aA0);  aA1 = fmaf(vA[l], w1v, aA1);
            aA2 = fmaf(vA[l], w2v, aA2); aA3 = fmaf(vA[l], w3, aA3);
            aB0 = fmaf(vB[l], w0, aB0);  aB1 = fmaf(vB[l], w1v, aB1);
            aB2 = fmaf(vB[l], w2v, aB2); aB3 = fmaf(vB[l], w3, aB3);
        }
        float hA[4], hB[4];
        hA[0] = g * gelu_f(aA0); hA[1] = g * gelu_f(aA1);
        hA[2] = g * gelu_f(aA2); hA[3] = g * gelu_f(aA3);
        hB[0] = g * gelu_f(aB0); hB[1] = g * gelu_f(aB1);
        hB[2] = g * gelu_f(aB2); hB[3] = g * gelu_f(aB3);
        #pragma unroll
        for (int l = L0; l < L1; ++l) {
            float accA = yA[CB + l - L0];
            float accB = yB[CB + l - L0];
            #pragma unroll
            for (int q = 0; q < 4; ++q) {
                const float w = w2[(jb * 4 + q) * P + l];
                accA = fmaf(hA[q], w, accA);
                accB = fmaf(hB[q], w, accB);
            }
            yA[CB + l - L0] = accA;
            yB[CB + l - L0] = accB;
        }
    }
    #pragma unroll
    for (int l = L0; l < L1; ++l) {
        yA[CB + l - L0] = fmaf(g, b2[l], yA[CB + l - L0]);
        yB[CB + l - L0] = fmaf(g, b2[l], yB[CB + l - L0]);
    }
}

// ================= K1: DFT + selection + trend/season + gating =================
__global__ __launch_bounds__(NTHREADS) void ams_k1(Params p) {
    __shared__ float xs[TT * XLD];       // 12.7 KB
    __shared__ float ct[96], st[96];
    __shared__ float xlin[96];
    __shared__ float selr[256], seli[256];   // [q][n]
    __shared__ int   selk[256];
    __shared__ int   selcnt[32];
    __shared__ float wst[32];
    __shared__ float gtmp[8];
    __shared__ float b0sh;

    const int tid = threadIdx.x;
    const int b = blockIdx.x;

    // ---- stage x, twiddles ----
    const float* xb = p.x + (size_t)b * (TT * TN);
    #pragma unroll 1
    for (int idx = tid; idx < TT * TN; idx += NTHREADS)
        xs[(idx >> 5) * XLD + (idx & 31)] = xb[idx];
    if (tid < 96) {
        float ang = (float)tid * 0.06544984694978735f;  // 2*pi/96
        ct[tid] = cosf(ang);
        st[tid] = sinf(ang);
    }
    if (tid < 32) wst[tid] = p.w_start[tid];
    if (tid == 0) b0sh = p.b_start[0];
    __syncthreads();

    // ---- Cooley-Tukey DFT (96 = 8x12) + fused wave-parallel top-3 ----
    {
        const int n = tid >> 3;
        const int kslot = tid & 7;
        const int lane = tid & 63;

        float Sr[12], Si[12];
        #pragma unroll
        for (int bb = 0; bb < 12; ++bb) { Sr[bb] = 0.0f; Si[bb] = 0.0f; }
        {
            const int step = 12 * kslot;
            int idx8 = 0;
            #pragma unroll 2
            for (int a = 0; a < 8; ++a) {
                float c8 = ct[idx8], s8 = st[idx8];
                idx8 += step; idx8 = (idx8 >= 96) ? idx8 - 96 : idx8;
                const float* xrow = &xs[(12 * a) * XLD + n];
                #pragma unroll
                for (int bb = 0; bb < 12; ++bb) {
                    float xv = xrow[bb * XLD];
                    Sr[bb] = fmaf(xv, c8, Sr[bb]);
                    Si[bb] = fmaf(xv, s8, Si[bb]);
                }
            }
        }

        float ar[7], ai[7];
        #pragma unroll
        for (int u = 0; u < 7; ++u) {
            const int k = kslot + 8 * u;
            const float ckv = ct[k];
            const float skv = st[k];
            float cb = 1.0f, sb = 0.0f, arx = 0.0f, aix = 0.0f;
            #pragma unroll
            for (int bb = 0; bb < 12; ++bb) {
                arx = fmaf(cb, Sr[bb], arx);
                arx = fmaf(-sb, Si[bb], arx);
                aix = fmaf(cb, Si[bb], aix);
                aix = fmaf(sb, Sr[bb], aix);
                float cn = fmaf(cb, ckv, -(sb * skv));
                float sn = fmaf(sb, ckv,  cb * skv);
                cb = cn; sb = sn;
            }
            ar[u] = arx; ai[u] = aix;
        }

        float amp[7];
        #pragma unroll
        for (int u = 0; u < 7; ++u) {
            int k = kslot + 8 * u;
            amp[u] = (k == 0) ? 0.0f : ((k <= 48) ? sqrtf(ar[u] * ar[u] + ai[u] * ai[u]) : -1.0f);
        }
        float v1 = -2.0f, v2 = -2.0f, v3 = -2.0f;
        #pragma unroll
        for (int u = 0; u < 7; ++u) {
            float a = amp[u];
            if (a > v1)      { v3 = v2; v2 = v1; v1 = a; }
            else if (a > v2) { v3 = v2; v2 = a; }
            else if (a > v3) { v3 = a; }
        }
        #pragma unroll
        for (int d = 1; d <= 4; d <<= 1) {
            float b1v = __shfl_xor(v1, d, 64);
            float b2v = __shfl_xor(v2, d, 64);
            float b3v = __shfl_xor(v3, d, 64);
            float m1 = fmaxf(v1, b1v), n1 = fminf(v1, b1v);
            float m2 = fmaxf(v2, b2v), n2 = fminf(v2, b2v);
            float s3 = (v1 > b1v) ? v3 : b3v;
            float c3 = fmaxf(fmaxf(fminf(n1, m2), n2), s3);
            v2 = fmaxf(n1, m2);
            v1 = m1;
            v3 = c3;
        }
        int qc = 0;
        #pragma unroll
        for (int u = 0; u < 7; ++u) qc += (amp[u] >= v3) ? 1 : 0;
        int inc = qc;
        #pragma unroll
        for (int d = 1; d <= 4; d <<= 1) {
            int t = __shfl_up(inc, d, 64);
            if (kslot >= d) inc += t;
        }
        int off = inc - qc;
        int cnt = __shfl(inc, lane | 7, 64);
        if (kslot == 0) selcnt[n] = (cnt < 8) ? cnt : 8;
        int w = off;
        #pragma unroll
        for (int u = 0; u < 7; ++u) {
            int k = kslot + 8 * u;
            if (amp[u] >= v3 && w < 8) {
                float wgt = (k == 0 || k == 48) ? (1.0f / 96.0f) : (2.0f / 96.0f);
                selk[w * 32 + n] = k;
                selr[w * 32 + n] = wgt * ar[u];
                seli[w * 32 + n] = wgt * ai[u];
                w++;
            }
        }
    }
    __syncthreads();

    // ---- trend + season -> x_lin (season via incremental rotators) ----
    {
        float b0 = b0sh;
        const int t0 = tid >> 5;
        const int n  = tid & 31;
        const int cnt = selcnt[n];
        float A0 = 0, B0 = 0, c0 = 1, s0 = 0, c80 = 1, s80 = 0;
        float A1 = 0, B1 = 0, c1 = 1, s1 = 0, c81 = 1, s81 = 0;
        float A2 = 0, B2 = 0, c2 = 1, s2 = 0, c82 = 1, s82 = 0;
        #define SETROT(Q, A, B, C, S, C8, S8) \
            if (Q < cnt) { \
                int k = selk[Q * 32 + n]; \
                A = selr[Q * 32 + n]; B = seli[Q * 32 + n]; \
                int m0 = (t0 * k) % 96; C = ct[m0]; S = st[m0]; \
                int m8 = (8 * k) % 96;  C8 = ct[m8]; S8 = st[m8]; \
            }
        SETROT(0, A0, B0, c0, s0, c80, s80)
        SETROT(1, A1, B1, c1, s1, c81, s81)
        SETROT(2, A2, B2, c2, s2, c82, s82)
        #undef SETROT
        #pragma unroll 1
        for (int j = 0; j < 12; ++j) {
            int t = t0 + 8 * j;
            float xv = xs[t * XLD + n];
            #define XC(tt) xs[(((tt) < 0) ? 0 : (((tt) > 95) ? 95 : (tt))) * XLD + n]
            float s4  = XC(t - 1) + xv + XC(t + 1) + XC(t + 2);
            float s8  = s4  + XC(t - 3) + XC(t - 2) + XC(t + 3) + XC(t + 4);
            float s12 = s8  + XC(t - 5) + XC(t - 4) + XC(t + 5) + XC(t + 6);
            #undef XC
            float trend = (s4 * 0.25f + s8 * 0.125f + s12 * (1.0f / 12.0f)) * (1.0f / 3.0f);
            float season = A0 * c0 + B0 * s0 + A1 * c1 + B1 * s1 + A2 * c2 + B2 * s2;
            float nc0 = fmaf(c0, c80, -(s0 * s80)), ns0 = fmaf(s0, c80, c0 * s80);
            float nc1 = fmaf(c1, c81, -(s1 * s81)), ns1 = fmaf(s1, c81, c1 * s81);
            float nc2 = fmaf(c2, c82, -(s2 * s82)), ns2 = fmaf(s2, c82, c2 * s82);
            c0 = nc0; s0 = ns0; c1 = nc1; s1 = ns1; c2 = nc2; s2 = ns2;
            #pragma unroll 1
            for (int q = 3; q < cnt; ++q) {
                int k = selk[q * 32 + n];
                int m = (t * k) % 96;
                season = fmaf(selr[q * 32 + n], ct[m], season);
                season = fmaf(seli[q * 32 + n], st[m], season);
            }
            float val = (xv + trend + season) * wst[n];
            #pragma unroll
            for (int d = 16; d >= 1; d >>= 1) val += __shfl_xor(val, d, 64);
            if ((tid & 31) == 0) xlin[t] = val + b0;
        }
    }
    __syncthreads();

    // ---- gating GEMV, all threads ----
    {
        int e8 = tid >> 5;
        int tl = tid & 31;
        int eb = e8 & 3;
        const float* W = ((e8 < 4) ? p.wg : p.wn) + eb * 96;
        float acc = 0.0f;
        #pragma unroll
        for (int c = 0; c < 3; ++c)
            acc = fmaf(xlin[tl + 32 * c], W[tl + 32 * c], acc);
        #pragma unroll
        for (int d = 16; d >= 1; d >>= 1) acc += __shfl_xor(acc, d, 64);
        if (tl == 0) gtmp[e8] = acc + ((e8 < 4) ? p.bg[eb] : p.bn[eb]);
    }
    __syncthreads();
    if (tid == 0) {
        float clean[4], stdv[4], noisy[4];
        #pragma unroll
        for (int e = 0; e < 4; ++e) {
            clean[e] = gtmp[e];
            float r = gtmp[4 + e];
            float sp = fmaxf(r, 0.0f) + log1pf(expf(-fabsf(r)));   // softplus
            stdv[e] = fminf(fmaxf(sp + 0.01f, 0.001f), 1000.0f);
            noisy[e] = clean[e] + p.noise[(size_t)b * 4 + e] * stdv[e];
        }
        int i1 = 0, i2 = -1;
        float v1 = -INFINITY, v2 = -INFINITY, v3 = -INFINITY;
        for (int e = 0; e < 4; ++e) if (noisy[e] > v1) { v1 = noisy[e]; i1 = e; }
        for (int e = 0; e < 4; ++e) if (e != i1 && noisy[e] > v2) { v2 = noisy[e]; i2 = e; }
        for (int e = 0; e < 4; ++e) if (e != i1 && e != i2 && noisy[e] > v3) { v3 = noisy[e]; }
        float e2 = expf(v2 - v1);
        float g1 = 1.0f / (1.0f + e2);
        float g2 = e2 * g1;
        float gates[4] = {0.0f, 0.0f, 0.0f, 0.0f};
        gates[i1] = g1; gates[i2] = g2;
        const float inv_sqrt2 = 0.7071067811865476f;
        #pragma unroll
        for (int e = 0; e < 4; ++e) {
            float thr = (noisy[e] > v3) ? v3 : v2;
            float z = (clean[e] - thr) / stdv[e];
            z = fminf(fmaxf(z, -50.0f), 50.0f);
            float pr = 0.5f * (1.0f + erff(z * inv_sqrt2));
            pr = fminf(fmaxf(pr, 0.0f), 1.0f);
            p.part[(size_t)b * 8 + e] = gates[e];
            p.part[(size_t)b * 8 + 4 + e] = pr;
        }
    }
}

// ====== K2: experts, 2 batches/block, weights via scalar K$ path (no LDS) ======
__global__ __launch_bounds__(NTHREADS) void ams_k2(Params p) {
    const int tid = threadIdx.x;
    // half 0: threads 0-127 -> batch 2b; half 1: threads 128-255 -> batch 2b+1
    const int half = tid >> 7;
    const size_t b = 2 * (size_t)blockIdx.x + half;
    const int g = tid & 127;
    // chunk pair (cA, cA+4); parity of cA == (g>>6) -> wave-uniform
    const int cA = ((g >> 5) & 1) * 2 + (g >> 6);
    const int cB = cA + 4;
    const int n = g & 31;

    const float g0 = p.part[b * 8 + 0];
    const float g1 = p.part[b * 8 + 1];
    const float g2 = p.part[b * 8 + 2];
    const float g3 = p.part[b * 8 + 3];
    const float* xg = p.x + b * (TT * TN);

    float yA[12], yB[12];
    #pragma unroll
    for (int r = 0; r < 12; ++r) { yA[r] = 0.0f; yB[r] = 0.0f; }

    if (g0 != 0.0f) {           // P=8; (cA&1) is wave-uniform
        if (cA & 1) {
            int pb = (3 * cA - 1) >> 1;
            patch_acc2<8, 4, 8, 0>(xg, p.ew[0], p.ew[2], p.ew[1], p.ew[3], pb,     pb + 6, n, g0, yA, yB);
            patch_acc2<8, 0, 8, 4>(xg, p.ew[0], p.ew[2], p.ew[1], p.ew[3], pb + 1, pb + 7, n, g0, yA, yB);
        } else {
            int pb = (3 * cA) >> 1;
            patch_acc2<8, 0, 8, 0>(xg, p.ew[0], p.ew[2], p.ew[1], p.ew[3], pb,     pb + 6, n, g0, yA, yB);
            patch_acc2<8, 0, 4, 8>(xg, p.ew[0], p.ew[2], p.ew[1], p.ew[3], pb + 1, pb + 7, n, g0, yA, yB);
        }
    }
    if (g1 != 0.0f) {           // P=6
        patch_acc2<6, 0, 6, 0>(xg, p.ew[4], p.ew[6], p.ew[5], p.ew[7], 2 * cA,     2 * cA + 8, n, g1, yA, yB);
        patch_acc2<6, 0, 6, 6>(xg, p.ew[4], p.ew[6], p.ew[5], p.ew[7], 2 * cA + 1, 2 * cA + 9, n, g1, yA, yB);
    }
    if (g2 != 0.0f) {           // P=4
        patch_acc2<4, 0, 4, 0>(xg, p.ew[8], p.ew[10], p.ew[9], p.ew[11], 3 * cA,     3 * cA + 12, n, g2, yA, yB);
        patch_acc2<4, 0, 4, 4>(xg, p.ew[8], p.ew[10], p.ew[9], p.ew[11], 3 * cA + 1, 3 * cA + 13, n, g2, yA, yB);
        patch_acc2<4, 0, 4, 8>(xg, p.ew[8], p.ew[10], p.ew[9], p.ew[11], 3 * cA + 2, 3 * cA + 14, n, g2, yA, yB);
    }
    if (g3 != 0.0f) {           // P=12
        patch_acc2<12, 0, 12, 0>(xg, p.ew[12], p.ew[14], p.ew[13], p.ew[15], cA, cB, n, g3, yA, yB);
    }

    float* ob = p.out + b * (TT * TN);
    float* obA = ob + (size_t)(12 * cA) * 32 + n;
    float* obB = ob + (size_t)(12 * cB) * 32 + n;
    #pragma unroll
    for (int r = 0; r < 12; ++r) {
        obA[r * 32] = yA[r];
        obB[r * 32] = yB[r];
    }
}

__global__ __launch_bounds__(NTHREADS) void ams_finalize(const float* __restrict__ part,
                                                         float* __restrict__ out_loss) {
    __shared__ float red[4][8];
    float acc[8] = {0, 0, 0, 0, 0, 0, 0, 0};
    #pragma unroll 1
    for (int r = threadIdx.x; r < TB; r += NTHREADS) {
        #pragma unroll
        for (int c = 0; c < 8; ++c) acc[c] += part[(size_t)r * 8 + c];
    }
    #pragma unroll
    for (int c = 0; c < 8; ++c) {
        #pragma unroll
        for (int d = 32; d >= 1; d >>= 1) acc[c] += __shfl_xor(acc[c], d, 64);
    }
    int wid = threadIdx.x >> 6;
    if ((threadIdx.x & 63) == 0) {
        #pragma unroll
        for (int c = 0; c < 8; ++c) red[wid][c] = acc[c];
    }
    __syncthreads();
    if (threadIdx.x == 0) {
        float imp[4], load[4];
        #pragma unroll
        for (int c = 0; c < 4; ++c) imp[c]  = red[0][c] + red[1][c] + red[2][c] + red[3][c];
        #pragma unroll
        for (int c = 0; c < 4; ++c) load[c] = red[0][4 + c] + red[1][4 + c] + red[2][4 + c] + red[3][4 + c];
        float mi = (imp[0] + imp[1] + imp[2] + imp[3]) * 0.25f;
        float vi = 0.0f;
        #pragma unroll
        for (int i = 0; i < 4; ++i) { float d = imp[i] - mi; vi += d * d; }
        vi *= (1.0f / 3.0f);
        float ml = (load[0] + load[1] + load[2] + load[3]) * 0.25f;
        float vl = 0.0f;
        #pragma unroll
        for (int i = 0; i < 4; ++i) { float d = load[i] - ml; vl += d * d; }
        vl *= (1.0f / 3.0f);
        float cvi = vi / (mi * mi + 1e-10f);
        float cvl = vl / (ml * ml + 1e-10f);
        out_loss[0] = (cvi + cvl) * 1e-4f;
    }
}

extern "C" void kernel_launch(void* const* d_in, const int* in_sizes, int n_in,
                              void* d_out, int out_size, void* d_ws, size_t ws_size,
                              hipStream_t stream) {
    Params p;
    p.x       = (const float*)d_in[0];
    p.noise   = (const float*)d_in[1];
    p.w_start = (const float*)d_in[2];
    p.b_start = (const float*)d_in[3];
    p.wg      = (const float*)d_in[4];
    p.bg      = (const float*)d_in[5];
    p.wn      = (const float*)d_in[6];
    p.bn      = (const float*)d_in[7];
    for (int i = 0; i < 16; ++i) p.ew[i] = (const float*)d_in[8 + i];
    p.out  = (float*)d_out;
    p.part = (float*)d_ws;   // 4096 * 8 floats = 128 KB of scratch

    ams_k1<<<TB, NTHREADS, 0, stream>>>(p);
    ams_k2<<<TB / 2, NTHREADS, 0, stream>>>(p);
    ams_finalize<<<1, NTHREADS, 0, stream>>>((const float*)d_ws,
                                             (float*)d_out + (size_t)TB * TT * TN);
}